// Round 2
// baseline (1058.073 us; speedup 1.0000x reference)
//
#include <hip/hip_runtime.h>
#include <math.h>

#define BLOCK 256
#define N_COLS 32768
#define VPT (N_COLS / (BLOCK * 4))   // 32 float4 per thread
#define NBINS 4096
#define CAND_CAP 3072

// Order-preserving float->uint key: larger float => larger key.
__device__ __forceinline__ unsigned key_of(unsigned b) {
    return b ^ (unsigned)(((int)b >> 31) | 0x80000000u);
}
__device__ __forceinline__ float val_of_key(unsigned k) {
    unsigned b = (k & 0x80000000u) ? (k ^ 0x80000000u) : ~k;
    return __uint_as_float(b);
}

// Inclusive prefix sum across 256 threads (4 waves of 64).
__device__ __forceinline__ int block_incl_scan(int v, int* ws) {
    const int lane = threadIdx.x & 63;
    const int w = threadIdx.x >> 6;
    #pragma unroll
    for (int d = 1; d < 64; d <<= 1) {
        int u = __shfl_up(v, d, 64);
        if (lane >= d) v += u;
    }
    if (lane == 63) ws[w] = v;
    __syncthreads();
    if (w == 1) v += ws[0];
    else if (w == 2) v += ws[0] + ws[1];
    else if (w == 3) v += ws[0] + ws[1] + ws[2];
    __syncthreads();
    return v;
}

__global__ __launch_bounds__(BLOCK, 2)
void mmcl_kernel(const float* __restrict__ inp, const int* __restrict__ tgt,
                 float* __restrict__ out, int K, float inv_m) {
    __shared__ int hist[NBINS];
    __shared__ unsigned cand[CAND_CAP];
    __shared__ int sh_cnt;
    __shared__ int sh_ws[4];
    __shared__ float sh_red[4];
    __shared__ float sh_max;
    __shared__ float sh_pos;
    __shared__ int sh_bstar;
    __shared__ int sh_need;
    __shared__ unsigned sh_prefix;

    const int tid = threadIdx.x;
    const int row = blockIdx.x;
    const long long base = (long long)row * N_COLS;
    const int target = tgt[row];

    for (int i = tid; i < NBINS; i += BLOCK) hist[i] = 0;
    if (tid == 0) {
        sh_cnt = 0;
        sh_pos = inp[base + target];
    }

    // ---- Pass A: load entire row into registers (single HBM touch) ----
    const float4* rowp = reinterpret_cast<const float4*>(inp + base);
    float4 v[VPT];
    #pragma unroll
    for (int j = 0; j < VPT; ++j) v[j] = rowp[j * BLOCK + tid];

    __syncthreads();  // hist zeroed

    float lmax = -INFINITY;
    #pragma unroll
    for (int j = 0; j < VPT; ++j) {
        float4 f = v[j];
        lmax = fmaxf(lmax, fmaxf(fmaxf(f.x, f.y), fmaxf(f.z, f.w)));
        atomicAdd(&hist[key_of(__float_as_uint(f.x)) >> 20], 1);
        atomicAdd(&hist[key_of(__float_as_uint(f.y)) >> 20], 1);
        atomicAdd(&hist[key_of(__float_as_uint(f.z)) >> 20], 1);
        atomicAdd(&hist[key_of(__float_as_uint(f.w)) >> 20], 1);
    }
    #pragma unroll
    for (int d = 32; d; d >>= 1) lmax = fmaxf(lmax, __shfl_down(lmax, d, 64));
    if ((tid & 63) == 0) sh_red[tid >> 6] = lmax;
    __syncthreads();  // histogram + per-wave maxes complete
    if (tid == 0) {
        sh_max = fmaxf(fmaxf(sh_red[0], sh_red[1]), fmaxf(sh_red[2], sh_red[3]));
        hist[key_of(__float_as_uint(sh_pos)) >> 20] -= 1;  // exclude positive exactly
    }
    __syncthreads();

    // ---- Find threshold bin: suffix scan from top, 16 bins per thread ----
    const int cstart = NBINS - 1 - tid * 16;
    int psum = 0;
    #pragma unroll
    for (int i = 0; i < 16; ++i) psum += hist[cstart - i];
    int incl = block_incl_scan(psum, sh_ws);
    int excl = incl - psum;
    if (excl < K && K <= incl) {
        int c = excl;
        #pragma unroll
        for (int i = 0; i < 16; ++i) {
            int h = hist[cstart - i];
            if (c + h >= K) { sh_bstar = cstart - i; sh_need = K - c; break; }
            c += h;
        }
    }
    __syncthreads();

    const int bstar = sh_bstar;
    const float M = 10.0f * sh_max;
    float S = 0.0f;

    // ---- Pass B over register-resident row: sum high bins, collect bin b* ----
#define PROC(x, col)                                                        \
    {                                                                       \
        unsigned kk = key_of(__float_as_uint(x));                           \
        int b = (int)(kk >> 20);                                            \
        if ((col) != target) {                                              \
            if (b > bstar) {                                                \
                S += __expf(fmaf(10.0f, (x), -M));                          \
            } else if (b == bstar) {                                        \
                int idx = atomicAdd(&sh_cnt, 1);                            \
                if (idx < CAND_CAP) cand[idx] = kk;                         \
            }                                                               \
        }                                                                   \
    }

    #pragma unroll
    for (int j = 0; j < VPT; ++j) {
        float4 f = v[j];
        const int col0 = (j * BLOCK + tid) * 4;
        PROC(f.x, col0 + 0)
        PROC(f.y, col0 + 1)
        PROC(f.z, col0 + 2)
        PROC(f.w, col0 + 3)
    }
#undef PROC
    __syncthreads();

    const int C = min(sh_cnt, CAND_CAP);
    if (tid == 0) sh_prefix = ((unsigned)bstar) << 20;
    __syncthreads();

    // ---- Exact radix-select of remaining 20 key bits among candidates ----
    const int shifts[3] = {12, 4, 0};
    const int nbs[3]    = {256, 256, 16};
    const unsigned kms[3] = {0xFFF00000u, 0xFFFFF000u, 0xFFFFFFF0u};
    for (int r = 0; r < 3; ++r) {
        hist[tid] = 0;
        __syncthreads();
        const unsigned pfx = sh_prefix;
        const int jn = sh_need;
        const int sh = shifts[r], nb = nbs[r];
        const unsigned km = kms[r];
        for (int i = tid; i < C; i += BLOCK) {
            unsigned kk = cand[i];
            if ((kk & km) == pfx) atomicAdd(&hist[(kk >> sh) & (nb - 1)], 1);
        }
        __syncthreads();
        int h = (tid < nb) ? hist[nb - 1 - tid] : 0;
        int inc2 = block_incl_scan(h, sh_ws);
        int exc2 = inc2 - h;
        if (tid < nb && exc2 < jn && jn <= inc2) {
            sh_prefix = pfx | ((unsigned)(nb - 1 - tid) << sh);
            sh_need = jn - exc2;
        }
        __syncthreads();
    }

    const unsigned tkey = sh_prefix;  // exact k-th largest negative (as key)
    const int need = sh_need;         // how many copies of tkey are in top-k
    for (int i = tid; i < C; i += BLOCK) {
        unsigned kk = cand[i];
        if (kk > tkey) S += __expf(fmaf(10.0f, val_of_key(kk), -M));
    }
    if (tid == 0) S += (float)need * __expf(fmaf(10.0f, val_of_key(tkey), -M));

    // ---- Reduce S, finish loss ----
    #pragma unroll
    for (int d = 32; d; d >>= 1) S += __shfl_down(S, d, 64);
    if ((tid & 63) == 0) sh_red[tid >> 6] = S;
    __syncthreads();
    if (tid == 0) {
        float pos10 = 10.0f * sh_pos;
        float Stot = sh_red[0] + sh_red[1] + sh_red[2] + sh_red[3]
                   + __expf(pos10 - M);
        float loss = M + logf(Stot) - pos10;
        atomicAdd(out, loss * inv_m);
    }
}

extern "C" void kernel_launch(void* const* d_in, const int* in_sizes, int n_in,
                              void* d_out, int out_size, void* d_ws, size_t ws_size,
                              hipStream_t stream) {
    const float* inp = (const float*)d_in[0];
    const int* tgt   = (const int*)d_in[1];
    float* out       = (float*)d_out;

    const int m = in_sizes[1];                 // 4096
    const long long total = in_sizes[0];       // m * n
    const int n = (int)(total / m);            // 32768 (kernel assumes this)
    const int K = (int)(0.01 * (n - 1));       // 327

    hipMemsetAsync(out, 0, sizeof(float), stream);
    mmcl_kernel<<<m, BLOCK, 0, stream>>>(inp, tgt, out, K, 1.0f / m);
}